// Round 4
// baseline (7016.995 us; speedup 1.0000x reference)
//
#include <hip/hip_runtime.h>
#include <cstddef>

#define DIN 128
#define DD 64

typedef unsigned short bfu;   // raw bf16 bits

static __device__ __forceinline__ float bf2f(bfu u) {
    union { unsigned int i; float f; } v; v.i = ((unsigned int)u) << 16; return v.f;
}
static __device__ __forceinline__ bfu f2bf(float f) {
    union { float f; unsigned int i; } v; v.f = f;
    unsigned int r = v.i + 0x7FFFu + ((v.i >> 16) & 1u);   // round-nearest-even
    return (bfu)(r >> 16);
}
static __device__ __forceinline__ float4 bf4_to_f4(ushort4 u) {
    return make_float4(bf2f(u.x), bf2f(u.y), bf2f(u.z), bf2f(u.w));
}
static __device__ __forceinline__ ushort4 f4_to_bf4(float4 f) {
    ushort4 u; u.x = f2bf(f.x); u.y = f2bf(f.y); u.z = f2bf(f.z); u.w = f2bf(f.w); return u;
}
static __device__ __forceinline__ float sigmoidf_(float x) {
    return 1.0f / (1.0f + __expf(-x));
}

// ---------------------------------------------------------------------------
// h0 = nodes_feat @ W_h + b_h     [N,128] @ [128,64] -> f32.  32 rows/block.
// ---------------------------------------------------------------------------
__global__ __launch_bounds__(256) void embed_h_v4(
    const float* __restrict__ x, const float* __restrict__ Wh,
    const float* __restrict__ bh, float* __restrict__ h, int N)
{
    __shared__ float w[DIN][DD];    // 32 KB
    __shared__ float xs[32][DIN];   // 16 KB
    for (int i = threadIdx.x; i < DIN * DD / 4; i += 256)
        ((float4*)w)[i] = ((const float4*)Wh)[i];
    int row0 = blockIdx.x * 32;
    for (int i = threadIdx.x; i < 32 * DIN / 4; i += 256) {
        int r = i >> 5, k = (i & 31) * 4;
        int row = row0 + r;
        float4 v = make_float4(0.f, 0.f, 0.f, 0.f);
        if (row < N) v = *(const float4*)(x + (size_t)row * DIN + k);
        *(float4*)(&xs[r][k]) = v;
    }
    __syncthreads();
    int rl = threadIdx.x >> 6;     // wave 0..3 -> rows rl*8 .. rl*8+7
    int c  = threadIdx.x & 63;
    float b = bh[c];
    for (int rr = 0; rr < 8; ++rr) {
        int r = rl * 8 + rr;
        int row = row0 + r;
        if (row >= N) break;
        float acc = b;
        #pragma unroll
        for (int k = 0; k < DIN; k += 4) {
            float4 xv = *(const float4*)(&xs[r][k]);
            acc += xv.x * w[k][c] + xv.y * w[k+1][c] + xv.z * w[k+2][c] + xv.w * w[k+3][c];
        }
        h[(size_t)row * DD + c] = acc;
    }
}

// ---------------------------------------------------------------------------
// e0[i,c] = edges_feat[i] * W_e[c] + b_e[c]  -> bf16
// ---------------------------------------------------------------------------
__global__ __launch_bounds__(256) void embed_e_v4(
    const float* __restrict__ ef, const float* __restrict__ We,
    const float* __restrict__ be, bfu* __restrict__ e, int E)
{
    int c = (threadIdx.x & 15) * 4;
    float4 w = *(const float4*)(We + c);
    float4 b = *(const float4*)(be + c);
    int total = E * 16;
    int stride = gridDim.x * blockDim.x;
    for (int u = blockIdx.x * blockDim.x + threadIdx.x; u < total; u += stride) {
        int edge = u >> 4;
        float f = ef[edge];
        float4 o;
        o.x = f * w.x + b.x; o.y = f * w.y + b.y;
        o.z = f * w.z + b.z; o.w = f * w.w + b.w;
        *(ushort4*)(e + (size_t)edge * DD + c) = f4_to_bf4(o);
    }
}

// ---------------------------------------------------------------------------
// Ah/Bh/Dh/Eh = h @ W{a,b,d,e}[l] + bias.  One wave per weight matrix,
// 64 rows of h (f32) per block; outputs bf16.
// ---------------------------------------------------------------------------
__global__ __launch_bounds__(256) void node_mm4_v4(
    const float* __restrict__ h,
    const float* __restrict__ Wa, const float* __restrict__ ba,
    const float* __restrict__ Wb, const float* __restrict__ bb,
    const float* __restrict__ Wd, const float* __restrict__ bd,
    const float* __restrict__ We, const float* __restrict__ be,
    bfu* __restrict__ Ah, bfu* __restrict__ Bh,
    bfu* __restrict__ Dh, bfu* __restrict__ Eh, int N)
{
    __shared__ float hs[64][DD];   // 16 KB
    int row0 = blockIdx.x * 64;
    for (int i = threadIdx.x; i < 64 * 16; i += 256) {
        int r = i >> 4, cc = (i & 15) * 4;
        int row = row0 + r;
        float4 v = make_float4(0.f, 0.f, 0.f, 0.f);
        if (row < N) v = *(const float4*)(h + (size_t)row * DD + cc);
        *(float4*)(&hs[r][cc]) = v;
    }
    __syncthreads();
    int m = threadIdx.x >> 6;   // wave id: 0=A 1=B 2=D 3=E
    int c = threadIdx.x & 63;
    const float* W    = (m == 0) ? Wa : (m == 1) ? Wb : (m == 2) ? Wd : We;
    const float* bias = (m == 0) ? ba : (m == 1) ? bb : (m == 2) ? bd : be;
    bfu*         Out  = (m == 0) ? Ah : (m == 1) ? Bh : (m == 2) ? Dh : Eh;
    float wcol[DD];
    #pragma unroll
    for (int k = 0; k < DD; ++k) wcol[k] = W[k * DD + c];
    float b = bias[c];
    int rmax = (N - row0 < 64) ? (N - row0) : 64;
    for (int r = 0; r < rmax; ++r) {
        float acc = b;
        #pragma unroll
        for (int k = 0; k < DD; k += 4) {
            float4 hv = *(const float4*)(&hs[r][k]);
            acc += hv.x * wcol[k] + hv.y * wcol[k+1] + hv.z * wcol[k+2] + hv.w * wcol[k+3];
        }
        Out[(size_t)(row0 + r) * DD + c] = f2bf(acc);
    }
}

// ---------------------------------------------------------------------------
// block-level per-channel (sum, sumsq) reduction; thread owns channels c..c+3
// where c = (tid&15)*4; lanes {l,l+16,l+32,l+48} share channels.
// ---------------------------------------------------------------------------
__device__ __forceinline__ void reduce_stats_256(
    float sacc[4], float sqacc[4], float (*red)[2][DD], float* __restrict__ stats_g)
{
    #pragma unroll
    for (int j = 0; j < 4; ++j) {
        float v = sacc[j], q = sqacc[j];
        v += __shfl_xor(v, 16); v += __shfl_xor(v, 32);
        q += __shfl_xor(q, 16); q += __shfl_xor(q, 32);
        sacc[j] = v; sqacc[j] = q;
    }
    int wv  = threadIdx.x >> 6;
    int inw = threadIdx.x & 63;
    int l16 = threadIdx.x & 15;
    if (inw < 16) {
        #pragma unroll
        for (int j = 0; j < 4; ++j) {
            red[wv][0][l16 * 4 + j] = sacc[j];
            red[wv][1][l16 * 4 + j] = sqacc[j];
        }
    }
    __syncthreads();
    if (threadIdx.x < DD) {
        float t  = red[0][0][threadIdx.x] + red[1][0][threadIdx.x]
                 + red[2][0][threadIdx.x] + red[3][0][threadIdx.x];
        float t2 = red[0][1][threadIdx.x] + red[1][1][threadIdx.x]
                 + red[2][1][threadIdx.x] + red[3][1][threadIdx.x];
        unsafeAtomicAdd(&stats_g[threadIdx.x], t);
        unsafeAtomicAdd(&stats_g[DD + threadIdx.x], t2);
    }
}

// ---------------------------------------------------------------------------
// edge pass 1: e_raw = (e@Wc+bc) + Dh[src] + Eh[dst];  sigma=sigmoid(e_raw)
//   num[dst] += sigma*Bh[src]; den[dst] += sigma   (f32 HW atomics)
//   BN stats of es = e_raw * enorm.  Nothing stored per-edge.
// ---------------------------------------------------------------------------
__global__ __launch_bounds__(256) void edge_pass1_v4(
    const bfu* __restrict__ e, const float* __restrict__ Wc, const float* __restrict__ bc,
    const bfu* __restrict__ Dh, const bfu* __restrict__ Eh, const bfu* __restrict__ Bh,
    const int* __restrict__ src, const int* __restrict__ dst,
    const float* __restrict__ enorm,
    float* __restrict__ num, float* __restrict__ den,
    float* __restrict__ stats, int E)
{
    __shared__ float wc[DD][DD];     // 16 KB
    __shared__ float bcs[DD];
    __shared__ float els[16][DD];    // 4 KB
    __shared__ float red[4][2][DD];  // 2 KB
    for (int i = threadIdx.x; i < DD * DD; i += 256) ((float*)wc)[i] = Wc[i];
    if (threadIdx.x < DD) bcs[threadIdx.x] = bc[threadIdx.x];

    int el  = threadIdx.x >> 4;
    int c   = (threadIdx.x & 15) * 4;
    float sacc[4]  = {0.f, 0.f, 0.f, 0.f};
    float sqacc[4] = {0.f, 0.f, 0.f, 0.f};

    int stride = gridDim.x * 16;
    for (int base = blockIdx.x * 16; base < E; base += stride) {
        __syncthreads();
        int eid = base + el;
        bool valid = eid < E;
        if (valid)
            *(float4*)(&els[el][c]) = bf4_to_f4(*(const ushort4*)(e + (size_t)eid * DD + c));
        __syncthreads();
        if (valid) {
            int s = src[eid], d = dst[eid];
            float en = enorm[eid];
            float4 acc = *(const float4*)(bcs + c);
            #pragma unroll
            for (int k = 0; k < DD; k += 4) {
                float4 ev = *(const float4*)(&els[el][k]);
                float4 w0 = *(const float4*)(&wc[k][c]);
                float4 w1 = *(const float4*)(&wc[k+1][c]);
                float4 w2 = *(const float4*)(&wc[k+2][c]);
                float4 w3 = *(const float4*)(&wc[k+3][c]);
                acc.x += ev.x*w0.x + ev.y*w1.x + ev.z*w2.x + ev.w*w3.x;
                acc.y += ev.x*w0.y + ev.y*w1.y + ev.z*w2.y + ev.w*w3.y;
                acc.z += ev.x*w0.z + ev.y*w1.z + ev.z*w2.z + ev.w*w3.z;
                acc.w += ev.x*w0.w + ev.y*w1.w + ev.z*w2.w + ev.w*w3.w;
            }
            float4 dh = bf4_to_f4(*(const ushort4*)(Dh + (size_t)s * DD + c));
            float4 eh = bf4_to_f4(*(const ushort4*)(Eh + (size_t)d * DD + c));
            float4 bh = bf4_to_f4(*(const ushort4*)(Bh + (size_t)s * DD + c));
            float4 er;
            er.x = acc.x + dh.x + eh.x; er.y = acc.y + dh.y + eh.y;
            er.z = acc.z + dh.z + eh.z; er.w = acc.w + dh.w + eh.w;
            float4 sg;
            sg.x = sigmoidf_(er.x); sg.y = sigmoidf_(er.y);
            sg.z = sigmoidf_(er.z); sg.w = sigmoidf_(er.w);
            float* np = num + (size_t)d * DD + c;
            float* dp = den + (size_t)d * DD + c;
            unsafeAtomicAdd(np + 0, sg.x * bh.x);
            unsafeAtomicAdd(np + 1, sg.y * bh.y);
            unsafeAtomicAdd(np + 2, sg.z * bh.z);
            unsafeAtomicAdd(np + 3, sg.w * bh.w);
            unsafeAtomicAdd(dp + 0, sg.x);
            unsafeAtomicAdd(dp + 1, sg.y);
            unsafeAtomicAdd(dp + 2, sg.z);
            unsafeAtomicAdd(dp + 3, sg.w);
            float es0 = er.x * en, es1 = er.y * en, es2 = er.z * en, es3 = er.w * en;
            sacc[0] += es0; sacc[1] += es1; sacc[2] += es2; sacc[3] += es3;
            sqacc[0] += es0*es0; sqacc[1] += es1*es1; sqacc[2] += es2*es2; sqacc[3] += es3*es3;
        }
    }
    __syncthreads();
    reduce_stats_256(sacc, sqacc, red, stats);
}

// ---------------------------------------------------------------------------
__global__ void bn_finalize_v4(const float* __restrict__ stats, float count,
                               float* __restrict__ bnp)
{
    int c = threadIdx.x;
    if (c < DD) {
        float mu  = stats[c] / count;
        float var = stats[DD + c] / count - mu * mu;
        bnp[c] = mu;
        bnp[DD + c] = rsqrtf(var + 1e-5f);
    }
}

// ---------------------------------------------------------------------------
// edge pass 2: recompute e_raw (identical FP order as pass 1), apply
// BN+ReLU+residual, store e in place (bf16).
// ---------------------------------------------------------------------------
__global__ __launch_bounds__(256) void edge_pass2_v4(
    bfu* __restrict__ e, const float* __restrict__ Wc, const float* __restrict__ bc,
    const bfu* __restrict__ Dh, const bfu* __restrict__ Eh,
    const int* __restrict__ src, const int* __restrict__ dst,
    const float* __restrict__ enorm, const float* __restrict__ bnp,
    const float* __restrict__ gamma, const float* __restrict__ beta, int E)
{
    __shared__ float wc[DD][DD];
    __shared__ float bcs[DD];
    __shared__ float els[16][DD];
    for (int i = threadIdx.x; i < DD * DD; i += 256) ((float*)wc)[i] = Wc[i];
    if (threadIdx.x < DD) bcs[threadIdx.x] = bc[threadIdx.x];

    int el = threadIdx.x >> 4;
    int c  = (threadIdx.x & 15) * 4;
    float4 mu = *(const float4*)(bnp + c);
    float4 is = *(const float4*)(bnp + DD + c);
    float4 g  = *(const float4*)(gamma + c);
    float4 bt = *(const float4*)(beta + c);

    int stride = gridDim.x * 16;
    for (int base = blockIdx.x * 16; base < E; base += stride) {
        __syncthreads();
        int eid = base + el;
        bool valid = eid < E;
        float4 ein = make_float4(0.f, 0.f, 0.f, 0.f);
        if (valid) {
            ein = bf4_to_f4(*(const ushort4*)(e + (size_t)eid * DD + c));
            *(float4*)(&els[el][c]) = ein;
        }
        __syncthreads();
        if (valid) {
            int s = src[eid], d = dst[eid];
            float en = enorm[eid];
            float4 acc = *(const float4*)(bcs + c);
            #pragma unroll
            for (int k = 0; k < DD; k += 4) {
                float4 ev = *(const float4*)(&els[el][k]);
                float4 w0 = *(const float4*)(&wc[k][c]);
                float4 w1 = *(const float4*)(&wc[k+1][c]);
                float4 w2 = *(const float4*)(&wc[k+2][c]);
                float4 w3 = *(const float4*)(&wc[k+3][c]);
                acc.x += ev.x*w0.x + ev.y*w1.x + ev.z*w2.x + ev.w*w3.x;
                acc.y += ev.x*w0.y + ev.y*w1.y + ev.z*w2.y + ev.w*w3.y;
                acc.z += ev.x*w0.z + ev.y*w1.z + ev.z*w2.z + ev.w*w3.z;
                acc.w += ev.x*w0.w + ev.y*w1.w + ev.z*w2.w + ev.w*w3.w;
            }
            float4 dh = bf4_to_f4(*(const ushort4*)(Dh + (size_t)s * DD + c));
            float4 eh = bf4_to_f4(*(const ushort4*)(Eh + (size_t)d * DD + c));
            float4 er;
            er.x = acc.x + dh.x + eh.x; er.y = acc.y + dh.y + eh.y;
            er.z = acc.z + dh.z + eh.z; er.w = acc.w + dh.w + eh.w;
            float4 y;
            float es;
            es = er.x * en; y.x = ein.x + fmaxf(g.x * (es - mu.x) * is.x + bt.x, 0.f);
            es = er.y * en; y.y = ein.y + fmaxf(g.y * (es - mu.y) * is.y + bt.y, 0.f);
            es = er.z * en; y.z = ein.z + fmaxf(g.z * (es - mu.z) * is.z + bt.z, 0.f);
            es = er.w * en; y.w = ein.w + fmaxf(g.w * (es - mu.w) * is.w + bt.w, 0.f);
            *(ushort4*)(e + (size_t)eid * DD + c) = f4_to_bf4(y);
        }
    }
}

// ---------------------------------------------------------------------------
// node stats: x = (Ah + num/(den+1e-6)) * nnorm;  BN stats only.
// ---------------------------------------------------------------------------
__global__ __launch_bounds__(256) void node_stats_v4(
    const bfu* __restrict__ Ah, const float* __restrict__ num,
    const float* __restrict__ den, const float* __restrict__ nnorm,
    float* __restrict__ stats, int N)
{
    __shared__ float red[4][2][DD];
    float sacc[4]  = {0.f, 0.f, 0.f, 0.f};
    float sqacc[4] = {0.f, 0.f, 0.f, 0.f};
    int total = N * 16;
    int stride = gridDim.x * blockDim.x;
    for (int u = blockIdx.x * blockDim.x + threadIdx.x; u < total; u += stride) {
        int n = u >> 4;
        size_t off = (size_t)n * DD + ((u & 15) * 4);
        float4 a  = bf4_to_f4(*(const ushort4*)(Ah + off));
        float4 nm = *(const float4*)(num + off);
        float4 dn = *(const float4*)(den + off);
        float nn = nnorm[n];
        float4 x;
        x.x = (a.x + nm.x / (dn.x + 1e-6f)) * nn;
        x.y = (a.y + nm.y / (dn.y + 1e-6f)) * nn;
        x.z = (a.z + nm.z / (dn.z + 1e-6f)) * nn;
        x.w = (a.w + nm.w / (dn.w + 1e-6f)) * nn;
        sacc[0] += x.x; sacc[1] += x.y; sacc[2] += x.z; sacc[3] += x.w;
        sqacc[0] += x.x*x.x; sqacc[1] += x.y*x.y; sqacc[2] += x.z*x.z; sqacc[3] += x.w*x.w;
    }
    __syncthreads();
    reduce_stats_256(sacc, sqacc, red, stats);
}

// ---------------------------------------------------------------------------
// h = h + relu(gamma*(x-mu)*istd + beta), x recomputed; h is f32.
// ---------------------------------------------------------------------------
__global__ __launch_bounds__(256) void node_apply_v4(
    const bfu* __restrict__ Ah, const float* __restrict__ num,
    const float* __restrict__ den, const float* __restrict__ nnorm,
    const float* __restrict__ bnp,
    const float* __restrict__ gamma, const float* __restrict__ beta,
    float* __restrict__ h, int N)
{
    int cc = (threadIdx.x & 15) * 4;
    float4 mu = *(const float4*)(bnp + cc);
    float4 is = *(const float4*)(bnp + DD + cc);
    float4 g  = *(const float4*)(gamma + cc);
    float4 b  = *(const float4*)(beta + cc);
    int total = N * 16;
    int stride = gridDim.x * blockDim.x;
    for (int u = blockIdx.x * blockDim.x + threadIdx.x; u < total; u += stride) {
        int n = u >> 4;
        size_t off = (size_t)n * DD + ((u & 15) * 4);
        float4 a  = bf4_to_f4(*(const ushort4*)(Ah + off));
        float4 nm = *(const float4*)(num + off);
        float4 dn = *(const float4*)(den + off);
        float nn = nnorm[n];
        float4 x;
        x.x = (a.x + nm.x / (dn.x + 1e-6f)) * nn;
        x.y = (a.y + nm.y / (dn.y + 1e-6f)) * nn;
        x.z = (a.z + nm.z / (dn.z + 1e-6f)) * nn;
        x.w = (a.w + nm.w / (dn.w + 1e-6f)) * nn;
        float4 hin = *(const float4*)(h + off);
        float4 y;
        y.x = hin.x + fmaxf(g.x * (x.x - mu.x) * is.x + b.x, 0.f);
        y.y = hin.y + fmaxf(g.y * (x.y - mu.y) * is.y + b.y, 0.f);
        y.z = hin.z + fmaxf(g.z * (x.z - mu.z) * is.z + b.z, 0.f);
        y.w = hin.w + fmaxf(g.w * (x.w - mu.w) * is.w + b.w, 0.f);
        *(float4*)(h + off) = y;
    }
}

// ---------------------------------------------------------------------------
// readout: hg[g] += h[n] (f32 atomics into ws); counts[g] += 1
// ---------------------------------------------------------------------------
__global__ __launch_bounds__(256) void readout_v4(
    const float* __restrict__ h, const int* __restrict__ gid,
    float* __restrict__ hg, float* __restrict__ counts, int N)
{
    int total = N * 16;
    int stride = gridDim.x * blockDim.x;
    for (int u = blockIdx.x * blockDim.x + threadIdx.x; u < total; u += stride) {
        int n = u >> 4;
        int c = (u & 15) * 4;
        int g = gid[n];
        float4 x = *(const float4*)(h + (size_t)n * DD + c);
        float* p = hg + (size_t)g * DD + c;
        unsafeAtomicAdd(p + 0, x.x);
        unsafeAtomicAdd(p + 1, x.y);
        unsafeAtomicAdd(p + 2, x.z);
        unsafeAtomicAdd(p + 3, x.w);
        if ((u & 15) == 0) unsafeAtomicAdd(&counts[g], 1.0f);
    }
}

__global__ void readout_div_v4(const float* __restrict__ hg,
                               const float* __restrict__ counts,
                               float* __restrict__ out, int GD)
{
    int i = blockIdx.x * blockDim.x + threadIdx.x;
    if (i < GD) {
        int g = i >> 6;
        out[i] = hg[i] / fmaxf(counts[g], 1.0f);
    }
}

// ---------------------------------------------------------------------------
extern "C" void kernel_launch(void* const* d_in, const int* in_sizes, int n_in,
                              void* d_out, int out_size, void* d_ws, size_t ws_size,
                              hipStream_t stream)
{
    const float* nodes_feat = (const float*)d_in[0];
    const float* edges_feat = (const float*)d_in[1];
    const float* nnorm      = (const float*)d_in[2];
    const float* enorm      = (const float*)d_in[3];
    const float* W_h = (const float*)d_in[4];
    const float* b_h = (const float*)d_in[5];
    const float* W_e = (const float*)d_in[6];
    const float* b_e = (const float*)d_in[7];
    const float* Wa  = (const float*)d_in[8];
    const float* ba  = (const float*)d_in[9];
    const float* Wb  = (const float*)d_in[10];
    const float* bb  = (const float*)d_in[11];
    const float* Wc  = (const float*)d_in[12];
    const float* bc  = (const float*)d_in[13];
    const float* Wd  = (const float*)d_in[14];
    const float* bd  = (const float*)d_in[15];
    const float* We_ = (const float*)d_in[16];
    const float* be_ = (const float*)d_in[17];
    const float* gamma_h = (const float*)d_in[18];
    const float* beta_h  = (const float*)d_in[19];
    const float* gamma_e = (const float*)d_in[20];
    const float* beta_e  = (const float*)d_in[21];
    const int* esrc = (const int*)d_in[22];
    const int* edst = (const int*)d_in[23];
    const int* gid  = (const int*)d_in[24];

    const int N = in_sizes[0] / DIN;
    const int E = in_sizes[1];
    const int G = out_size / DD;
    const int L = in_sizes[8] / (DD * DD);

    // -------- workspace layout: f32 region, then bf16 region (~167 MB) -----
    float* f = (float*)d_ws;
    float* h       = f; f += (size_t)N * DD;
    float* numb    = f; f += (size_t)N * DD;   // } one memset region
    float* denb    = f; f += (size_t)N * DD;   // }
    float* stats_e = f; f += 128;              // }
    float* stats_h = f; f += 128;              // }
    float* bnp     = f; f += 128;
    float* hg      = f; f += (size_t)G * DD;   // } one memset region
    float* counts  = f; f += G;                // }
    bfu* bb_ = (bfu*)f;
    bfu* Ah = bb_; bb_ += (size_t)N * DD;
    bfu* Bh = bb_; bb_ += (size_t)N * DD;
    bfu* Dh = bb_; bb_ += (size_t)N * DD;
    bfu* Eh = bb_; bb_ += (size_t)N * DD;
    bfu* e  = bb_; bb_ += (size_t)E * DD;

    dim3 blk(256);

    hipMemsetAsync(hg, 0, ((size_t)G * DD + G) * sizeof(float), stream);

    embed_h_v4<<<(N + 31) / 32, blk, 0, stream>>>(nodes_feat, W_h, b_h, h, N);
    embed_e_v4<<<2048, blk, 0, stream>>>(edges_feat, W_e, b_e, e, E);

    for (int l = 0; l < L; ++l) {
        node_mm4_v4<<<(N + 63) / 64, blk, 0, stream>>>(
            h, Wa + (size_t)l * DD * DD, ba + (size_t)l * DD,
            Wb + (size_t)l * DD * DD, bb + (size_t)l * DD,
            Wd + (size_t)l * DD * DD, bd + (size_t)l * DD,
            We_ + (size_t)l * DD * DD, be_ + (size_t)l * DD,
            Ah, Bh, Dh, Eh, N);
        hipMemsetAsync(numb, 0, ((size_t)2 * N * DD + 256) * sizeof(float), stream);
        edge_pass1_v4<<<2048, blk, 0, stream>>>(
            e, Wc + (size_t)l * DD * DD, bc + (size_t)l * DD,
            Dh, Eh, Bh, esrc, edst, enorm, numb, denb, stats_e, E);
        bn_finalize_v4<<<1, 64, 0, stream>>>(stats_e, (float)E, bnp);
        edge_pass2_v4<<<2048, blk, 0, stream>>>(
            e, Wc + (size_t)l * DD * DD, bc + (size_t)l * DD,
            Dh, Eh, esrc, edst, enorm, bnp,
            gamma_e + (size_t)l * DD, beta_e + (size_t)l * DD, E);
        node_stats_v4<<<1024, blk, 0, stream>>>(Ah, numb, denb, nnorm, stats_h, N);
        bn_finalize_v4<<<1, 64, 0, stream>>>(stats_h, (float)N, bnp);
        node_apply_v4<<<1024, blk, 0, stream>>>(
            Ah, numb, denb, nnorm, bnp,
            gamma_h + (size_t)l * DD, beta_h + (size_t)l * DD, h, N);
    }

    readout_v4<<<1024, blk, 0, stream>>>(h, gid, hg, counts, N);
    readout_div_v4<<<(G * DD + 255) / 256, blk, 0, stream>>>(
        hg, counts, (float*)d_out, G * DD);
}

// Round 5
// 2493.019 us; speedup vs baseline: 2.8147x; 2.8147x over previous
//
#include <hip/hip_runtime.h>
#include <cstddef>

#define DIN 128
#define DD 64

typedef unsigned short bfu;   // raw bf16 bits

static __device__ __forceinline__ float bf2f(bfu u) {
    union { unsigned int i; float f; } v; v.i = ((unsigned int)u) << 16; return v.f;
}
static __device__ __forceinline__ bfu f2bf(float f) {
    union { float f; unsigned int i; } v; v.f = f;
    unsigned int r = v.i + 0x7FFFu + ((v.i >> 16) & 1u);   // round-nearest-even
    return (bfu)(r >> 16);
}
static __device__ __forceinline__ float4 bf4_to_f4(ushort4 u) {
    return make_float4(bf2f(u.x), bf2f(u.y), bf2f(u.z), bf2f(u.w));
}
static __device__ __forceinline__ ushort4 f4_to_bf4(float4 f) {
    ushort4 u; u.x = f2bf(f.x); u.y = f2bf(f.y); u.z = f2bf(f.z); u.w = f2bf(f.w); return u;
}
static __device__ __forceinline__ float sigmoidf_(float x) {
    return 1.0f / (1.0f + __expf(-x));
}
static __device__ __forceinline__ float readlane_f(float v, int lane) {
    return __uint_as_float(__builtin_amdgcn_readlane(__float_as_uint(v), lane));
}

// ---------------------------------------------------------------------------
// h0 = nodes_feat @ W_h + b_h     [N,128] @ [128,64] -> f32.  32 rows/block.
// ---------------------------------------------------------------------------
__global__ __launch_bounds__(256) void embed_h_v5(
    const float* __restrict__ x, const float* __restrict__ Wh,
    const float* __restrict__ bh, float* __restrict__ h, int N)
{
    __shared__ float w[DIN][DD];    // 32 KB
    __shared__ float xs[32][DIN];   // 16 KB
    for (int i = threadIdx.x; i < DIN * DD / 4; i += 256)
        ((float4*)w)[i] = ((const float4*)Wh)[i];
    int row0 = blockIdx.x * 32;
    for (int i = threadIdx.x; i < 32 * DIN / 4; i += 256) {
        int r = i >> 5, k = (i & 31) * 4;
        int row = row0 + r;
        float4 v = make_float4(0.f, 0.f, 0.f, 0.f);
        if (row < N) v = *(const float4*)(x + (size_t)row * DIN + k);
        *(float4*)(&xs[r][k]) = v;
    }
    __syncthreads();
    int rl = threadIdx.x >> 6;
    int c  = threadIdx.x & 63;
    float b = bh[c];
    for (int rr = 0; rr < 8; ++rr) {
        int r = rl * 8 + rr;
        int row = row0 + r;
        if (row >= N) break;
        float acc = b;
        #pragma unroll
        for (int k = 0; k < DIN; k += 4) {
            float4 xv = *(const float4*)(&xs[r][k]);
            acc += xv.x * w[k][c] + xv.y * w[k+1][c] + xv.z * w[k+2][c] + xv.w * w[k+3][c];
        }
        h[(size_t)row * DD + c] = acc;
    }
}

// ---------------------------------------------------------------------------
// e0[i,c] = edges_feat[i] * W_e[c] + b_e[c]  -> bf16
// ---------------------------------------------------------------------------
__global__ __launch_bounds__(256) void embed_e_v5(
    const float* __restrict__ ef, const float* __restrict__ We,
    const float* __restrict__ be, bfu* __restrict__ e, int E)
{
    int c = (threadIdx.x & 15) * 4;
    float4 w = *(const float4*)(We + c);
    float4 b = *(const float4*)(be + c);
    int total = E * 16;
    int stride = gridDim.x * blockDim.x;
    for (int u = blockIdx.x * blockDim.x + threadIdx.x; u < total; u += stride) {
        int edge = u >> 4;
        float f = ef[edge];
        float4 o;
        o.x = f * w.x + b.x; o.y = f * w.y + b.y;
        o.z = f * w.z + b.z; o.w = f * w.w + b.w;
        *(ushort4*)(e + (size_t)edge * DD + c) = f4_to_bf4(o);
    }
}

// ---------------------------------------------------------------------------
// CSR build: histogram -> 3-phase exclusive scan -> scatter
// ---------------------------------------------------------------------------
__global__ void csr_hist_v5(const int* __restrict__ dst, int* __restrict__ counts, int E)
{
    for (int i = blockIdx.x * blockDim.x + threadIdx.x; i < E; i += gridDim.x * blockDim.x)
        atomicAdd(&counts[dst[i]], 1);
}

__global__ void csr_scan_a_v5(const int* __restrict__ counts, int* __restrict__ part,
                              int M, int CH)
{
    __shared__ int sd[256];
    int b = blockIdx.x, t = threadIdx.x;
    int idx = b * CH + t;
    int v = (t < CH && idx < M) ? counts[idx] : 0;
    sd[t] = v; __syncthreads();
    for (int off = 128; off > 0; off >>= 1) {
        if (t < off) sd[t] += sd[t + off];
        __syncthreads();
    }
    if (t == 0) part[b] = sd[0];
}

__global__ void csr_scan_b_v5(int* __restrict__ part)
{
    __shared__ int sd[256];
    int t = threadIdx.x;
    int v = part[t];
    sd[t] = v; __syncthreads();
    for (int off = 1; off < 256; off <<= 1) {
        int u = (t >= off) ? sd[t - off] : 0;
        __syncthreads();
        sd[t] += u;
        __syncthreads();
    }
    part[t] = sd[t] - v;   // exclusive
}

__global__ void csr_scan_c_v5(const int* __restrict__ counts, const int* __restrict__ part,
                              int* __restrict__ offsets, int* __restrict__ cursor,
                              int M, int CH)
{
    __shared__ int sd[256];
    int b = blockIdx.x, t = threadIdx.x;
    int idx = b * CH + t;
    int v = (t < CH && idx < M) ? counts[idx] : 0;
    sd[t] = v; __syncthreads();
    for (int off = 1; off < 256; off <<= 1) {
        int u = (t >= off) ? sd[t - off] : 0;
        __syncthreads();
        sd[t] += u;
        __syncthreads();
    }
    int excl = sd[t] - v + part[b];
    if (t < CH && idx < M) { offsets[idx] = excl; cursor[idx] = excl; }
}

__global__ void csr_scatter_v5(const int* __restrict__ dst, int* __restrict__ cursor,
                               int* __restrict__ csr_eid, int E)
{
    for (int i = blockIdx.x * blockDim.x + threadIdx.x; i < E; i += gridDim.x * blockDim.x) {
        int p = atomicAdd(&cursor[dst[i]], 1);
        csr_eid[p] = i;
    }
}

// ---------------------------------------------------------------------------
// Ah/Bh/Dh/Eh = h @ W{a,b,d,e}[l] + bias.  One wave per weight matrix.
// ---------------------------------------------------------------------------
__global__ __launch_bounds__(256) void node_mm4_v5(
    const float* __restrict__ h,
    const float* __restrict__ Wa, const float* __restrict__ ba,
    const float* __restrict__ Wb, const float* __restrict__ bb,
    const float* __restrict__ Wd, const float* __restrict__ bd,
    const float* __restrict__ We, const float* __restrict__ be,
    bfu* __restrict__ Ah, bfu* __restrict__ Bh,
    bfu* __restrict__ Dh, bfu* __restrict__ Eh, int N)
{
    __shared__ float hs[64][DD];   // 16 KB
    int row0 = blockIdx.x * 64;
    for (int i = threadIdx.x; i < 64 * 16; i += 256) {
        int r = i >> 4, cc = (i & 15) * 4;
        int row = row0 + r;
        float4 v = make_float4(0.f, 0.f, 0.f, 0.f);
        if (row < N) v = *(const float4*)(h + (size_t)row * DD + cc);
        *(float4*)(&hs[r][cc]) = v;
    }
    __syncthreads();
    int m = threadIdx.x >> 6;
    int c = threadIdx.x & 63;
    const float* W    = (m == 0) ? Wa : (m == 1) ? Wb : (m == 2) ? Wd : We;
    const float* bias = (m == 0) ? ba : (m == 1) ? bb : (m == 2) ? bd : be;
    bfu*         Out  = (m == 0) ? Ah : (m == 1) ? Bh : (m == 2) ? Dh : Eh;
    float wcol[DD];
    #pragma unroll
    for (int k = 0; k < DD; ++k) wcol[k] = W[k * DD + c];
    float b = bias[c];
    int rmax = (N - row0 < 64) ? (N - row0) : 64;
    for (int r = 0; r < rmax; ++r) {
        float acc = b;
        #pragma unroll
        for (int k = 0; k < DD; k += 4) {
            float4 hv = *(const float4*)(&hs[r][k]);
            acc += hv.x * wcol[k] + hv.y * wcol[k+1] + hv.z * wcol[k+2] + hv.w * wcol[k+3];
        }
        Out[(size_t)(row0 + r) * DD + c] = f2bf(acc);
    }
}

// ---------------------------------------------------------------------------
// fused node-centric accumulation: one WAVE per dst node, lane = channel.
// Recomputes er per in-edge (readlane broadcast of the e row against a
// register-resident Wc column), accumulates num/den in REGISTERS (no
// atomics), BN-e stats (es per edge) and BN-h stats (x per node).
// Writes hraw = (Ah + num/(den+1e-6)) * nnorm.
// stats layout: [0:64) sum es | [64:128) sum es^2 | [128:192) sum x | [192:256) sum x^2
// ---------------------------------------------------------------------------
__global__ __launch_bounds__(256) void fused_accum_v5(
    const bfu* __restrict__ e, const float* __restrict__ Wc, const float* __restrict__ bc,
    const bfu* __restrict__ Ah, const bfu* __restrict__ Bh,
    const bfu* __restrict__ Dh, const bfu* __restrict__ Eh,
    const int* __restrict__ csr_eid, const int* __restrict__ offsets,
    const int* __restrict__ src,
    const float* __restrict__ enorm, const float* __restrict__ nnorm,
    float* __restrict__ hraw, float* __restrict__ stats, int N)
{
    __shared__ float red[4][4][DD];
    int wid = threadIdx.x >> 6;
    int c   = threadIdx.x & 63;
    float wcol[DD];
    #pragma unroll
    for (int k = 0; k < DD; ++k) wcol[k] = Wc[k * DD + c];
    float bcc = bc[c];
    float se = 0.f, se2 = 0.f, sh = 0.f, sh2 = 0.f;

    int gw = blockIdx.x * 4 + wid;
    int gstride = gridDim.x * 4;
    for (int n = gw; n < N; n += gstride) {
        int j0 = offsets[n], j1 = offsets[n + 1];
        float ehv = bf2f(Eh[(size_t)n * DD + c]);
        float num = 0.f, den = 0.f;
        for (int j = j0; j < j1; ++j) {
            int eid  = csr_eid[j];
            int s    = src[eid];
            float en = enorm[eid];
            float ev = bf2f(e[(size_t)eid * DD + c]);
            float er0 = bcc, er1 = 0.f, er2 = 0.f, er3 = 0.f;
            #pragma unroll
            for (int k = 0; k < DD; k += 4) {
                er0 += readlane_f(ev, k)     * wcol[k];
                er1 += readlane_f(ev, k + 1) * wcol[k + 1];
                er2 += readlane_f(ev, k + 2) * wcol[k + 2];
                er3 += readlane_f(ev, k + 3) * wcol[k + 3];
            }
            float er = ((er0 + er1) + (er2 + er3))
                     + bf2f(Dh[(size_t)s * DD + c]) + ehv;
            float sg = sigmoidf_(er);
            num += sg * bf2f(Bh[(size_t)s * DD + c]);
            den += sg;
            float es = er * en;
            se += es; se2 += es * es;
        }
        float x = (bf2f(Ah[(size_t)n * DD + c]) + num / (den + 1e-6f)) * nnorm[n];
        hraw[(size_t)n * DD + c] = x;
        sh += x; sh2 += x * x;
    }

    red[wid][0][c] = se;  red[wid][1][c] = se2;
    red[wid][2][c] = sh;  red[wid][3][c] = sh2;
    __syncthreads();
    if (threadIdx.x < DD) {
        int t = threadIdx.x;
        float t0 = 0.f, t1 = 0.f, t2 = 0.f, t3 = 0.f;
        #pragma unroll
        for (int w = 0; w < 4; ++w) {
            t0 += red[w][0][t]; t1 += red[w][1][t];
            t2 += red[w][2][t]; t3 += red[w][3][t];
        }
        unsafeAtomicAdd(&stats[t], t0);
        unsafeAtomicAdd(&stats[DD + t], t1);
        unsafeAtomicAdd(&stats[2 * DD + t], t2);
        unsafeAtomicAdd(&stats[3 * DD + t], t3);
    }
}

// ---------------------------------------------------------------------------
// finalize both BNs: bnp[0:64)=mu_e [64:128)=istd_e [128:192)=mu_h [192:256)=istd_h
// ---------------------------------------------------------------------------
__global__ void bn_fin2_v5(const float* __restrict__ stats, float Ecnt, float Ncnt,
                           float* __restrict__ bnp)
{
    int t = threadIdx.x;   // 128 threads
    if (t < DD) {
        float mu  = stats[t] / Ecnt;
        float var = stats[DD + t] / Ecnt - mu * mu;
        bnp[t] = mu;
        bnp[DD + t] = rsqrtf(var + 1e-5f);
    } else {
        int cc = t - DD;
        float mu  = stats[2 * DD + cc] / Ncnt;
        float var = stats[3 * DD + cc] / Ncnt - mu * mu;
        bnp[2 * DD + cc] = mu;
        bnp[3 * DD + cc] = rsqrtf(var + 1e-5f);
    }
}

// ---------------------------------------------------------------------------
// edge apply: recompute e_raw, apply BN_e + ReLU + residual, store e (bf16).
// ---------------------------------------------------------------------------
__global__ __launch_bounds__(256) void edge_apply_v5(
    bfu* __restrict__ e, const float* __restrict__ Wc, const float* __restrict__ bc,
    const bfu* __restrict__ Dh, const bfu* __restrict__ Eh,
    const int* __restrict__ src, const int* __restrict__ dst,
    const float* __restrict__ enorm, const float* __restrict__ bnp,
    const float* __restrict__ gamma, const float* __restrict__ beta, int E)
{
    __shared__ float wc[DD][DD];
    __shared__ float bcs[DD];
    __shared__ float els[16][DD];
    for (int i = threadIdx.x; i < DD * DD; i += 256) ((float*)wc)[i] = Wc[i];
    if (threadIdx.x < DD) bcs[threadIdx.x] = bc[threadIdx.x];

    int el = threadIdx.x >> 4;
    int c  = (threadIdx.x & 15) * 4;
    float4 mu = *(const float4*)(bnp + c);
    float4 is = *(const float4*)(bnp + DD + c);
    float4 g  = *(const float4*)(gamma + c);
    float4 bt = *(const float4*)(beta + c);

    int stride = gridDim.x * 16;
    for (int base = blockIdx.x * 16; base < E; base += stride) {
        __syncthreads();
        int eid = base + el;
        bool valid = eid < E;
        float4 ein = make_float4(0.f, 0.f, 0.f, 0.f);
        if (valid) {
            ein = bf4_to_f4(*(const ushort4*)(e + (size_t)eid * DD + c));
            *(float4*)(&els[el][c]) = ein;
        }
        __syncthreads();
        if (valid) {
            int s = src[eid], d = dst[eid];
            float en = enorm[eid];
            float4 acc = *(const float4*)(bcs + c);
            #pragma unroll
            for (int k = 0; k < DD; k += 4) {
                float4 ev = *(const float4*)(&els[el][k]);
                float4 w0 = *(const float4*)(&wc[k][c]);
                float4 w1 = *(const float4*)(&wc[k+1][c]);
                float4 w2 = *(const float4*)(&wc[k+2][c]);
                float4 w3 = *(const float4*)(&wc[k+3][c]);
                acc.x += ev.x*w0.x + ev.y*w1.x + ev.z*w2.x + ev.w*w3.x;
                acc.y += ev.x*w0.y + ev.y*w1.y + ev.z*w2.y + ev.w*w3.y;
                acc.z += ev.x*w0.z + ev.y*w1.z + ev.z*w2.z + ev.w*w3.z;
                acc.w += ev.x*w0.w + ev.y*w1.w + ev.z*w2.w + ev.w*w3.w;
            }
            float4 dh = bf4_to_f4(*(const ushort4*)(Dh + (size_t)s * DD + c));
            float4 eh = bf4_to_f4(*(const ushort4*)(Eh + (size_t)d * DD + c));
            float4 er;
            er.x = acc.x + dh.x + eh.x; er.y = acc.y + dh.y + eh.y;
            er.z = acc.z + dh.z + eh.z; er.w = acc.w + dh.w + eh.w;
            float4 y;
            float es;
            es = er.x * en; y.x = ein.x + fmaxf(g.x * (es - mu.x) * is.x + bt.x, 0.f);
            es = er.y * en; y.y = ein.y + fmaxf(g.y * (es - mu.y) * is.y + bt.y, 0.f);
            es = er.z * en; y.z = ein.z + fmaxf(g.z * (es - mu.z) * is.z + bt.z, 0.f);
            es = er.w * en; y.w = ein.w + fmaxf(g.w * (es - mu.w) * is.w + bt.w, 0.f);
            *(ushort4*)(e + (size_t)eid * DD + c) = f4_to_bf4(y);
        }
    }
}

// ---------------------------------------------------------------------------
// h = h + relu(gamma*(hraw-mu)*istd + beta); h, hraw f32.
// ---------------------------------------------------------------------------
__global__ __launch_bounds__(256) void node_apply_v5(
    const float* __restrict__ hraw, const float* __restrict__ bnph,
    const float* __restrict__ gamma, const float* __restrict__ beta,
    float* __restrict__ h, int N)
{
    int cc = (threadIdx.x & 15) * 4;
    float4 mu = *(const float4*)(bnph + cc);
    float4 is = *(const float4*)(bnph + DD + cc);
    float4 g  = *(const float4*)(gamma + cc);
    float4 b  = *(const float4*)(beta + cc);
    int total = N * 16;
    int stride = gridDim.x * blockDim.x;
    for (int u = blockIdx.x * blockDim.x + threadIdx.x; u < total; u += stride) {
        size_t off = ((size_t)(u >> 4)) * DD + ((u & 15) * 4);
        float4 x   = *(const float4*)(hraw + off);
        float4 hin = *(const float4*)(h + off);
        float4 y;
        y.x = hin.x + fmaxf(g.x * (x.x - mu.x) * is.x + b.x, 0.f);
        y.y = hin.y + fmaxf(g.y * (x.y - mu.y) * is.y + b.y, 0.f);
        y.z = hin.z + fmaxf(g.z * (x.z - mu.z) * is.z + b.z, 0.f);
        y.w = hin.w + fmaxf(g.w * (x.w - mu.w) * is.w + b.w, 0.f);
        *(float4*)(h + off) = y;
    }
}

// ---------------------------------------------------------------------------
// readout: hg[g] += h[n] (f32 atomics); counts[g] += 1; then divide.
// ---------------------------------------------------------------------------
__global__ __launch_bounds__(256) void readout_v5(
    const float* __restrict__ h, const int* __restrict__ gid,
    float* __restrict__ hg, float* __restrict__ counts, int N)
{
    int total = N * 16;
    int stride = gridDim.x * blockDim.x;
    for (int u = blockIdx.x * blockDim.x + threadIdx.x; u < total; u += stride) {
        int n = u >> 4;
        int c = (u & 15) * 4;
        int g = gid[n];
        float4 x = *(const float4*)(h + (size_t)n * DD + c);
        float* p = hg + (size_t)g * DD + c;
        unsafeAtomicAdd(p + 0, x.x);
        unsafeAtomicAdd(p + 1, x.y);
        unsafeAtomicAdd(p + 2, x.z);
        unsafeAtomicAdd(p + 3, x.w);
        if ((u & 15) == 0) unsafeAtomicAdd(&counts[g], 1.0f);
    }
}

__global__ void readout_div_v5(const float* __restrict__ hg,
                               const float* __restrict__ counts,
                               float* __restrict__ out, int GD)
{
    int i = blockIdx.x * blockDim.x + threadIdx.x;
    if (i < GD) {
        int g = i >> 6;
        out[i] = hg[i] / fmaxf(counts[g], 1.0f);
    }
}

// ---------------------------------------------------------------------------
extern "C" void kernel_launch(void* const* d_in, const int* in_sizes, int n_in,
                              void* d_out, int out_size, void* d_ws, size_t ws_size,
                              hipStream_t stream)
{
    const float* nodes_feat = (const float*)d_in[0];
    const float* edges_feat = (const float*)d_in[1];
    const float* nnorm      = (const float*)d_in[2];
    const float* enorm      = (const float*)d_in[3];
    const float* W_h = (const float*)d_in[4];
    const float* b_h = (const float*)d_in[5];
    const float* W_e = (const float*)d_in[6];
    const float* b_e = (const float*)d_in[7];
    const float* Wa  = (const float*)d_in[8];
    const float* ba  = (const float*)d_in[9];
    const float* Wb  = (const float*)d_in[10];
    const float* bb  = (const float*)d_in[11];
    const float* Wc  = (const float*)d_in[12];
    const float* bc  = (const float*)d_in[13];
    const float* Wd  = (const float*)d_in[14];
    const float* bd  = (const float*)d_in[15];
    const float* We_ = (const float*)d_in[16];
    const float* be_ = (const float*)d_in[17];
    const float* gamma_h = (const float*)d_in[18];
    const float* beta_h  = (const float*)d_in[19];
    const float* gamma_e = (const float*)d_in[20];
    const float* beta_e  = (const float*)d_in[21];
    const int* esrc = (const int*)d_in[22];
    const int* edst = (const int*)d_in[23];
    const int* gid  = (const int*)d_in[24];

    const int N = in_sizes[0] / DIN;
    const int E = in_sizes[1];
    const int G = out_size / DD;
    const int L = in_sizes[8] / (DD * DD);

    // -------- workspace layout: f32/int region, then bf16 region (~157 MB) --
    const int Npad = ((N + 1 + 3) / 4) * 4;
    float* f = (float*)d_ws;
    float* h     = f; f += (size_t)N * DD;
    float* hraw  = f; f += (size_t)N * DD;
    float* stats = f; f += 256;
    float* bnp   = f; f += 256;
    float* hg    = f; f += (size_t)G * DD;   // } zeroed together
    float* gcnt  = f; f += G;                // }
    int* ccounts = (int*)f; f += Npad;       // } zeroed together
    int* coffs   = (int*)f; f += Npad;
    int* ccursor = (int*)f; f += Npad;
    int* cpart   = (int*)f; f += 256;
    int* csr_eid = (int*)f; f += (size_t)E;
    bfu* bb_ = (bfu*)f;
    bfu* Ah = bb_; bb_ += (size_t)N * DD;
    bfu* Bh = bb_; bb_ += (size_t)N * DD;
    bfu* Dh = bb_; bb_ += (size_t)N * DD;
    bfu* Eh = bb_; bb_ += (size_t)N * DD;
    bfu* e  = bb_; bb_ += (size_t)E * DD;

    dim3 blk(256);

    hipMemsetAsync(hg, 0, ((size_t)G * DD + G) * sizeof(float), stream);
    hipMemsetAsync(ccounts, 0, (size_t)Npad * sizeof(int), stream);

    embed_h_v5<<<(N + 31) / 32, blk, 0, stream>>>(nodes_feat, W_h, b_h, h, N);
    embed_e_v5<<<2048, blk, 0, stream>>>(edges_feat, W_e, b_e, e, E);

    // CSR by dst (once per call)
    const int M  = N + 1;
    const int CH = (M + 255) / 256;
    csr_hist_v5<<<2048, blk, 0, stream>>>(edst, ccounts, E);
    csr_scan_a_v5<<<256, blk, 0, stream>>>(ccounts, cpart, M, CH);
    csr_scan_b_v5<<<1, blk, 0, stream>>>(cpart);
    csr_scan_c_v5<<<256, blk, 0, stream>>>(ccounts, cpart, coffs, ccursor, M, CH);
    csr_scatter_v5<<<2048, blk, 0, stream>>>(edst, ccursor, csr_eid, E);

    for (int l = 0; l < L; ++l) {
        node_mm4_v5<<<(N + 63) / 64, blk, 0, stream>>>(
            h, Wa + (size_t)l * DD * DD, ba + (size_t)l * DD,
            Wb + (size_t)l * DD * DD, bb + (size_t)l * DD,
            Wd + (size_t)l * DD * DD, bd + (size_t)l * DD,
            We_ + (size_t)l * DD * DD, be_ + (size_t)l * DD,
            Ah, Bh, Dh, Eh, N);
        hipMemsetAsync(stats, 0, 256 * sizeof(float), stream);
        fused_accum_v5<<<1024, blk, 0, stream>>>(
            e, Wc + (size_t)l * DD * DD, bc + (size_t)l * DD,
            Ah, Bh, Dh, Eh, csr_eid, coffs, esrc, enorm, nnorm,
            hraw, stats, N);
        bn_fin2_v5<<<1, 128, 0, stream>>>(stats, (float)E, (float)N, bnp);
        edge_apply_v5<<<2048, blk, 0, stream>>>(
            e, Wc + (size_t)l * DD * DD, bc + (size_t)l * DD,
            Dh, Eh, esrc, edst, enorm, bnp,
            gamma_e + (size_t)l * DD, beta_e + (size_t)l * DD, E);
        node_apply_v5<<<1024, blk, 0, stream>>>(
            hraw, bnp + 2 * DD,
            gamma_h + (size_t)l * DD, beta_h + (size_t)l * DD, h, N);
    }

    readout_v5<<<1024, blk, 0, stream>>>(h, gid, hg, gcnt, N);
    readout_div_v5<<<(G * DD + 255) / 256, blk, 0, stream>>>(
        hg, gcnt, (float*)d_out, G * DD);
}